// Round 8
// baseline (21.902 us; speedup 1.0000x reference)
//
#include <hip/hip_runtime.h>

#define KH 512
#define KW 512
#define TW 4

typedef float f32x2 __attribute__((ext_vector_type(2)));

__global__ __launch_bounds__(256)
void TrainableFilter_75118978007282_kernel(const float* __restrict__ x,
                                           const float* __restrict__ wsp,
                                           float* __restrict__ out) {
    // block (64,4); each thread computes TW=4 adjacent pixels of one row.
    // Window per row = cols [w0-2, w0+5] loaded as x2 + x4 + x2 (32B exact).
    const int tx = threadIdx.x;
    const int w0 = blockIdx.x * (64 * TW) + tx * TW;
    const int h  = blockIdx.y * 4 + threadIdx.y;
    const int plane = blockIdx.z;
    const float* __restrict__ xp = x + (size_t)plane * KH * KW;

    const bool left  = (w0 == 0);
    const bool right = (w0 == KW - TW);
    // clamped segment bases (stay in-bounds; reflected values fixed by selects)
    const int bA = left  ? 0        : (w0 - 2);   // 8B-aligned (w0%4==0)
    const int bC = right ? (KW - 2) : (w0 + 4);   // 8B-aligned

    // center-tap (ki=2,j=2): d==0, g==wsp[12] -> folded into den init
    const float w12 = wsp[12];
    f32x2 num01 = {0.f, 0.f}, num23 = {0.f, 0.f};
    f32x2 den01 = {w12, w12}, den23 = {w12, w12};
    f32x2 c01, c23;

    const float NC2 = -0.72134752f;  // -0.5*log2(e): exp(-0.5 d^2)=exp2(d^2*NC2)

    // row order {2,0,1,3,4}: row 2 first so centers come from its window
    const int order[5] = {2, 0, 1, 3, 4};
#pragma unroll
    for (int rr = 0; rr < 5; ++rr) {
        const int ki = order[rr];
        int hh = h + ki - 2;
        hh = (hh < 0) ? -hh : hh;
        hh = (hh >= KH) ? (2 * KH - 2 - hh) : hh;
        const float* __restrict__ rp = xp + (size_t)hh * KW;

        const f32x2  sA = *reinterpret_cast<const f32x2*>(rp + bA);
        const float4 sB = *reinterpret_cast<const float4*>(rp + w0);
        const f32x2  sC = *reinterpret_cast<const f32x2*>(rp + bC);
        // win[i] = col w0-2+i
        float win[8] = { sA.x, sA.y, sB.x, sB.y, sB.z, sB.w, sC.x, sC.y };
        // reflect fixups (only 2 selects, rest land correct by clamping):
        //  left  (w0==0,  bA->0):   win[0] wants col -2 -> 2 = win[4]; win[1] wants -1 -> 1 (already)
        //  right (w0==508, bC->510): win[6] wants 512 -> 510 (already); win[7] wants 513 -> 509 = win[3]
        win[0] = left  ? win[4] : win[0];
        win[7] = right ? win[3] : win[7];

        if (ki == 2) {              // centers = cols w0..w0+3
            c01.x = win[2]; c01.y = win[3];
            c23.x = win[4]; c23.y = win[5];
        }

#pragma unroll
        for (int j = 0; j < 5; ++j) {
            if (ki == 2 && j == 2) continue;    // folded into den init
            const float wkv = wsp[ki * 5 + j];  // uniform -> SGPR
            {
                const f32x2 p = {win[j], win[j + 1]};
                const f32x2 d = p - c01;
                const f32x2 t = d * NC2;
                const f32x2 a = d * t;          // d^2 * NC2 (<=0)
                f32x2 e;
                e.x = __builtin_amdgcn_exp2f(a.x);
                e.y = __builtin_amdgcn_exp2f(a.y);
                const f32x2 g = e * wkv;
                num01 = num01 + g * d;
                den01 = den01 + g;
            }
            {
                const f32x2 p = {win[j + 2], win[j + 3]};
                const f32x2 d = p - c23;
                const f32x2 t = d * NC2;
                const f32x2 a = d * t;
                f32x2 e;
                e.x = __builtin_amdgcn_exp2f(a.x);
                e.y = __builtin_amdgcn_exp2f(a.y);
                const f32x2 g = e * wkv;
                num23 = num23 + g * d;
                den23 = den23 + g;
            }
        }
    }

    float4 o;
    o.x = c01.x + __fdividef(num01.x, den01.x);
    o.y = c01.y + __fdividef(num01.y, den01.y);
    o.z = c23.x + __fdividef(num23.x, den23.x);
    o.w = c23.y + __fdividef(num23.y, den23.y);
    *reinterpret_cast<float4*>(out + (size_t)plane * KH * KW + (size_t)h * KW + w0) = o;
}

extern "C" void kernel_launch(void* const* d_in, const int* in_sizes, int n_in,
                              void* d_out, int out_size, void* d_ws, size_t ws_size,
                              hipStream_t stream) {
    const float* x   = (const float*)d_in[0];
    const float* wsp = (const float*)d_in[1];
    float* out = (float*)d_out;

    const int planes = out_size / (KH * KW);  // B*C = 12

    dim3 block(64, 4, 1);
    dim3 grid(KW / (64 * TW), KH / 4, planes);
    TrainableFilter_75118978007282_kernel<<<grid, block, 0, stream>>>(x, wsp, out);
}